// Round 19
// baseline (207.557 us; speedup 1.0000x reference)
//
#include <hip/hip_runtime.h>
#include <hip/hip_bf16.h>

// Sizes (fixed by the problem)
#define BATCH   8
#define SEQ     512     // Q_LEN == K_LEN
#define DMODEL  512
#define NHEAD   8
#define DKH     64

typedef __attribute__((ext_vector_type(8))) short bf16x8;
typedef __attribute__((ext_vector_type(4))) float f32x4;

// HW RNE conversion: compiler lowers pairs to v_cvt_pk_bf16_f32 (gfx950),
// replacing the old 3-4 VALU-op manual round per element (m240: compiler-
// generated cvt beats hand asm). Bitwise-identical RNE for non-NaN inputs.
__device__ __forceinline__ short f2bf(float f) {
    __hip_bfloat16 h = __float2bfloat16(f);
    return *(short*)&h;
}
__device__ __forceinline__ float bf2f(short s) {
    union { unsigned u; float f; } v; v.u = ((unsigned)(unsigned short)s) << 16;
    return v.f;
}

// LDS tile: rows x 32 k (bf16), padded row stride 40 elems (80B): 2-way alias, free.
#define LDK 40

// Stage 64x32 f32 -> bf16 LDS tile. 256 threads: r=tid>>2, 8 elems each.
__device__ __forceinline__ void stage_f32(const float* __restrict__ base,
                                          int rstride, short* lds, int tid) {
    int r = tid >> 2, c = (tid & 3) << 3;
    const float* p = base + (size_t)r * rstride + c;
    float4 x = *(const float4*)p;
    float4 y = *(const float4*)(p + 4);
    union { short s[8]; bf16x8 v; } o;
    o.s[0] = f2bf(x.x); o.s[1] = f2bf(x.y); o.s[2] = f2bf(x.z); o.s[3] = f2bf(x.w);
    o.s[4] = f2bf(y.x); o.s[5] = f2bf(y.y); o.s[6] = f2bf(y.z); o.s[7] = f2bf(y.w);
    *(bf16x8*)(lds + r * LDK + c) = o.v;
}

// Stage 64x32 bf16 -> LDS tile.
__device__ __forceinline__ void stage_bf16(const short* __restrict__ base,
                                           int rstride, short* lds, int tid) {
    int r = tid >> 2, c = (tid & 3) << 3;
    bf16x8 v = *(const bf16x8*)(base + (size_t)r * rstride + c);
    *(bf16x8*)(lds + r * LDK + c) = v;
}

// One 32-deep K-step: 4 waves, each wave does a 32x32 quadrant = 4 MFMAs.
__device__ __forceinline__ void mma_tile(const short* As, const short* Bs,
                                         int lane, int wm, int wn, f32x4 acc[2][2]) {
    int lo = lane & 15, hi = lane >> 4;
    bf16x8 a0 = *(const bf16x8*)(As + (wm * 32 + lo) * LDK + hi * 8);
    bf16x8 a1 = *(const bf16x8*)(As + (wm * 32 + 16 + lo) * LDK + hi * 8);
    bf16x8 b0 = *(const bf16x8*)(Bs + (wn * 32 + lo) * LDK + hi * 8);
    bf16x8 b1 = *(const bf16x8*)(Bs + (wn * 32 + 16 + lo) * LDK + hi * 8);
    acc[0][0] = __builtin_amdgcn_mfma_f32_16x16x32_bf16(a0, b0, acc[0][0], 0, 0, 0);
    acc[0][1] = __builtin_amdgcn_mfma_f32_16x16x32_bf16(a0, b1, acc[0][1], 0, 0, 0);
    acc[1][0] = __builtin_amdgcn_mfma_f32_16x16x32_bf16(a1, b0, acc[1][0], 0, 0, 0);
    acc[1][1] = __builtin_amdgcn_mfma_f32_16x16x32_bf16(a1, b1, acc[1][1], 0, 0, 0);
}

// ---------------- Q/K/V projection + Wr transpose (merged) ----------------
__global__ __launch_bounds__(256) void qkvw_kernel(
        const float* __restrict__ query, const float* __restrict__ key_,
        const float* __restrict__ value,
        const float* __restrict__ Wq, const float* __restrict__ Wk,
        const float* __restrict__ Wv, const float* __restrict__ Wr,
        const float* __restrict__ uvec, const float* __restrict__ vvec,
        short* __restrict__ Qu, short* __restrict__ Qv,
        short* __restrict__ Kh, short* __restrict__ Vt,
        short* __restrict__ Wrt) {
    __shared__ short As[64 * LDK], Bs[64 * LDK];
    int f = blockIdx.x, tid = threadIdx.x;
    if (f >= 1536) {                       // Wr transpose path
        int base = (f - 1536) * 1024;
        #pragma unroll
        for (int j = 0; j < 4; j++) {
            int idx = base + j * 256 + tid;
            int n = idx >> 9, m = idx & 511;
            Wrt[idx] = f2bf(Wr[(size_t)m * 512 + n]);
        }
        return;
    }
    int i = f >> 3;                       // 0..191
    int nt = i & 7;
    int gm = (f & 7) * 24 + (i >> 3);     // 0..191 = (mode,mt)
    int mode = gm >> 6, mt = gm & 63;
    const float* x = mode == 0 ? query : (mode == 1 ? key_ : value);
    const float* W = mode == 0 ? Wq : (mode == 1 ? Wk : Wv);
    int lane = tid & 63, w = tid >> 6, wm = w >> 1, wn = w & 1;
    const float* Abase = x + (size_t)mt * 64 * DMODEL;
    const float* Bbase = W + (size_t)nt * 64 * DMODEL;
    f32x4 acc[2][2] = {};
    for (int kt = 0; kt < DMODEL; kt += 32) {
        __syncthreads();
        stage_f32(Abase + kt, DMODEL, As, tid);
        stage_f32(Bbase + kt, DMODEL, Bs, tid);
        __syncthreads();
        mma_tile(As, Bs, lane, wm, wn, acc);
    }
    int lo = lane & 15, hi = lane >> 4;
    for (int fm = 0; fm < 2; fm++)
        for (int fn = 0; fn < 2; fn++)
            for (int r = 0; r < 4; r++) {
                int m = mt * 64 + wm * 32 + fm * 16 + hi * 4 + r;
                int n = nt * 64 + wn * 32 + fn * 16 + lo;
                float val = acc[fm][fn][r];
                int b = m >> 9, s = m & 511, h = n >> 6, d = n & 63;
                if (mode == 0) {
                    size_t idx = ((size_t)(b * NHEAD + h) * SEQ + s) * DKH + d;
                    Qu[idx] = f2bf(val + uvec[n]);
                    Qv[idx] = f2bf(val + vvec[n]);
                } else if (mode == 1) {
                    Kh[((size_t)(b * NHEAD + h) * SEQ + s) * DKH + d] = f2bf(val);
                } else {
                    Vt[((size_t)(b * NHEAD + h) * DKH + d) * SEQ + s] = f2bf(val);
                }
            }
}

// -------- merged t + content (independent stages, one launch) --------
// blocks 0..4095:    T2[q][bh][n] = sum_d Qv[b,h,q,d] * Wrt[n][h*64+d]
// blocks 4096..6399: scores[bh,q,k] = Qu . Kh  ('=', COMPACT causal tiles:
//                    2304 = 8 XCD x 8 bh x 36 triangular (qt,kt_) pairs)
__global__ __launch_bounds__(256) void tc_kernel(const short* __restrict__ Qv,
                                                 const short* __restrict__ Wrt,
                                                 short* __restrict__ T2,
                                                 const short* __restrict__ Qu,
                                                 const short* __restrict__ Kh,
                                                 float* __restrict__ scores) {
    __shared__ short As[64 * LDK], Bs[64 * LDK];
    int f0 = blockIdx.x, tid = threadIdx.x;
    int lane = tid & 63, w = tid >> 6, wm = w >> 1, wn = w & 1;
    int lo = lane & 15, hi = lane >> 4;
    if (f0 < 4096) {                       // ---- t path ----
        int f = f0;
        int i = f >> 3;                    // 0..511
        int nt = i & 7;
        int mh = (f & 7) * 64 + (i >> 3);  // 0..511
        int mt = mh >> 3, h = mh & 7;
        int m0 = mt * 64, b = m0 >> 9, q0 = m0 & 511;
        const short* Abase = Qv + ((size_t)(b * NHEAD + h) * SEQ + q0) * DKH;
        const short* Bbase = Wrt + (size_t)nt * 64 * DMODEL + h * DKH;
        f32x4 acc[2][2] = {};
        for (int kt = 0; kt < DKH; kt += 32) {
            __syncthreads();
            stage_bf16(Abase + kt, DKH, As, tid);
            stage_bf16(Bbase + kt, DMODEL, Bs, tid);
            __syncthreads();
            mma_tile(As, Bs, lane, wm, wn, acc);
        }
        int bh = b * NHEAD + h;
        for (int fm = 0; fm < 2; fm++)
            for (int fn = 0; fn < 2; fn++)
                for (int r = 0; r < 4; r++) {
                    int q = q0 + wm * 32 + fm * 16 + hi * 4 + r;
                    int n = nt * 64 + wn * 32 + fn * 16 + lo;
                    T2[((size_t)q * 64 + bh) * DMODEL + n] = f2bf(acc[fm][fn][r]);
                }
    } else {                               // ---- content path (compacted) ----
        int i = f0 - 4096;                 // 0..2303
        int x = i & 7, j = i >> 3;         // j 0..287
        int bhl = j / 36, t = j % 36;      // 8 bh-locals x 36 causal tiles
        int bh = x * 8 + bhl;
        int qt = 0, base = 0;
        #pragma unroll
        for (int s = 1; s <= 7; s++) { if (t >= base + qt + 1) { base += qt + 1; qt++; } }
        int kt_ = t - base;                // kt_ <= qt guaranteed
        const short* Abase = Qu + ((size_t)bh * SEQ + qt * 64) * DKH;
        const short* Bbase = Kh + ((size_t)bh * SEQ + kt_ * 64) * DKH;
        f32x4 acc[2][2] = {};
        for (int kt = 0; kt < DKH; kt += 32) {
            __syncthreads();
            stage_bf16(Abase + kt, DKH, As, tid);
            stage_bf16(Bbase + kt, DKH, Bs, tid);
            __syncthreads();
            mma_tile(As, Bs, lane, wm, wn, acc);
        }
        for (int fm = 0; fm < 2; fm++)
            for (int fn = 0; fn < 2; fn++)
                for (int r = 0; r < 4; r++) {
                    int q = qt * 64 + wm * 32 + fm * 16 + hi * 4 + r;
                    int k = kt_ * 64 + wn * 32 + fn * 16 + lo;
                    scores[((size_t)bh * SEQ + q) * SEQ + k] = acc[fm][fn][r];
                }
    }
}

// ---- position v9: one q per 1024-thread block (16 waves x 32k = full row) ----
// T2[q] (64KB) staged ONCE; waves with kbase>q idle after the single barrier.
// Block pairing: q and 511-q halves balance causal load. XCD-balanced by bk&7.
__global__ __launch_bounds__(1024) void position_kernel(const short* __restrict__ T2,
                                                        const float* __restrict__ rel,
                                                        float* __restrict__ scores) {
    int bk = blockIdx.x;
    int x = bk & 7, idx = bk >> 3;         // idx 0..63
    int q = (idx < 32) ? (idx * 8 + x) : (511 - ((idx - 32) * 8 + x));
    __shared__ short Tl[64 * 512];         // 64KB
    int tid = threadIdx.x, w = tid >> 6, lane = tid & 63;
    const short* Tq = T2 + (size_t)q * (64 * DMODEL);
    #pragma unroll
    for (int it = 0; it < 4; ++it) {       // 1024 thr x 16B = 16KB/iter, sequential
        int chunk = it * 1024 + tid;       // 0..4095
        int r = chunk >> 6, c = chunk & 63;
        bf16x8 v = *(const bf16x8*)(Tq + (size_t)chunk * 8);
        *(bf16x8*)(Tl + r * 512 + (c ^ (r & 7)) * 8) = v;
    }
    __syncthreads();
    int kbase = w * 32;
    if (kbase > q) return;                 // wave-level causal skip (post-barrier)
    int lo = lane & 15, hi = lane >> 4;
    const float* relq = rel + ((size_t)kbase * SEQ + q) * DMODEL;
    f32x4 acc[4][2] = {};
    for (int n = 0; n < DMODEL; n += 32) {
        bf16x8 a[4];
        #pragma unroll
        for (int fm = 0; fm < 4; fm++) {
            int rr = fm * 16 + lo;
            int g = ((n >> 3) + hi) ^ (rr & 7);
            a[fm] = *(const bf16x8*)(Tl + rr * 512 + g * 8);
        }
        bf16x8 bfrag[2];
        #pragma unroll
        for (int fk = 0; fk < 2; fk++) {
            const float* p = relq + (size_t)(fk * 16 + lo) * (SEQ * DMODEL) + n + hi * 8;
            float4 xv = *(const float4*)p;
            float4 yv = *(const float4*)(p + 4);
            union { short s[8]; bf16x8 v; } o;
            o.s[0] = f2bf(xv.x); o.s[1] = f2bf(xv.y); o.s[2] = f2bf(xv.z); o.s[3] = f2bf(xv.w);
            o.s[4] = f2bf(yv.x); o.s[5] = f2bf(yv.y); o.s[6] = f2bf(yv.z); o.s[7] = f2bf(yv.w);
            bfrag[fk] = o.v;
        }
        #pragma unroll
        for (int fm = 0; fm < 4; fm++) {
            acc[fm][0] = __builtin_amdgcn_mfma_f32_16x16x32_bf16(a[fm], bfrag[0], acc[fm][0], 0, 0, 0);
            acc[fm][1] = __builtin_amdgcn_mfma_f32_16x16x32_bf16(a[fm], bfrag[1], acc[fm][1], 0, 0, 0);
        }
    }
    #pragma unroll
    for (int fm = 0; fm < 4; fm++)
        #pragma unroll
        for (int fk = 0; fk < 2; fk++)
            #pragma unroll
            for (int r = 0; r < 4; r++) {
                int bh = fm * 16 + hi * 4 + r;
                int k = kbase + fk * 16 + lo;
                scores[((size_t)bh * SEQ + q) * SEQ + k] += acc[fm][fk][r];
            }
}

// ------- pv_sm3: single-pass M=0 softmax + weights + PV (LDS P, Vt direct) ---
// CU-level causal balance: complementary qt across the two dispatch rounds.
#define PSTR 520
__global__ __launch_bounds__(256) void pv_sm_kernel(float* __restrict__ scores,
                                                    const short* __restrict__ Vt,
                                                    short* __restrict__ attn) {
    __shared__ short Ps[64 * PSTR];        // 66.6KB
    __shared__ float invS_lds[64];
    int f = blockIdx.x;
    int i = f >> 3;                        // 0..63 (per-XCD index)
    int bhl, qt;
    if (i < 32) { bhl = i >> 3;            qt = i & 7; }
    else        { bhl = 4 + ((i - 32) >> 3); qt = 7 - (i & 7); }
    int bh = (f & 7) * 8 + bhl;
    int tid = threadIdx.x, lane = tid & 63, w = tid >> 6, wm = w >> 1, wn = w & 1;
    int kmax = (qt + 1) * 64;
    int r = tid >> 2, c4 = tid & 3;
    int q = qt * 64 + r;
    int cc = c4 * 8;
    float* row = scores + ((size_t)bh * SEQ + q) * SEQ;
    // ---- single pass: P = exp(x/8) (M=0), S accumulate, P -> LDS ----
    float S = 0.f;
    for (int kt = 0; kt < kmax; kt += 32) {
        float4 x = *(const float4*)(row + kt + cc);
        float4 y = *(const float4*)(row + kt + cc + 4);
        float p0 = (kt + cc + 0 <= q) ? __expf(x.x * 0.125f) : 0.f;
        float p1 = (kt + cc + 1 <= q) ? __expf(x.y * 0.125f) : 0.f;
        float p2 = (kt + cc + 2 <= q) ? __expf(x.z * 0.125f) : 0.f;
        float p3 = (kt + cc + 3 <= q) ? __expf(x.w * 0.125f) : 0.f;
        float p4 = (kt + cc + 4 <= q) ? __expf(y.x * 0.125f) : 0.f;
        float p5 = (kt + cc + 5 <= q) ? __expf(y.y * 0.125f) : 0.f;
        float p6 = (kt + cc + 6 <= q) ? __expf(y.z * 0.125f) : 0.f;
        float p7 = (kt + cc + 7 <= q) ? __expf(y.w * 0.125f) : 0.f;
        S += p0 + p1 + p2 + p3 + p4 + p5 + p6 + p7;
        union { short s[8]; bf16x8 v; } o;
        o.s[0] = f2bf(p0); o.s[1] = f2bf(p1); o.s[2] = f2bf(p2); o.s[3] = f2bf(p3);
        o.s[4] = f2bf(p4); o.s[5] = f2bf(p5); o.s[6] = f2bf(p6); o.s[7] = f2bf(p7);
        *(bf16x8*)(Ps + r * PSTR + kt + cc) = o.v;
    }
    S += __shfl_xor(S, 1); S += __shfl_xor(S, 2);
    float invS = 1.0f / S;
    if (c4 == 0) invS_lds[r] = invS;
    // ---- weights write: full 512 row, normalized (zeros beyond kmax) ----
    for (int kt = 0; kt < SEQ; kt += 32) {
        float4 o0, o1;
        if (kt < kmax) {
            const short* pr = Ps + r * PSTR + kt + cc;
            o0 = make_float4(bf2f(pr[0]) * invS, bf2f(pr[1]) * invS,
                             bf2f(pr[2]) * invS, bf2f(pr[3]) * invS);
            o1 = make_float4(bf2f(pr[4]) * invS, bf2f(pr[5]) * invS,
                             bf2f(pr[6]) * invS, bf2f(pr[7]) * invS);
        } else {
            o0 = make_float4(0.f, 0.f, 0.f, 0.f); o1 = o0;
        }
        *(float4*)(row + kt + cc) = o0;
        *(float4*)(row + kt + cc + 4) = o1;
    }
    __syncthreads();                       // publish Ps + invS_lds
    // ---- PV: acc += P(LDS) x Vt(global direct), scale by invS at epilogue ----
    const short* Vtb = Vt + (size_t)bh * DKH * SEQ;
    int lo = lane & 15, hi = lane >> 4;
    f32x4 acc[2][2] = {};
    for (int kc = 0; kc < kmax; kc += 32) {
        bf16x8 a0 = *(const bf16x8*)(Ps + (wm * 32 + lo) * PSTR + kc + hi * 8);
        bf16x8 a1 = *(const bf16x8*)(Ps + (wm * 32 + 16 + lo) * PSTR + kc + hi * 8);
        bf16x8 b0 = *(const bf16x8*)(Vtb + (size_t)(wn * 32 + lo) * SEQ + kc + hi * 8);
        bf16x8 b1 = *(const bf16x8*)(Vtb + (size_t)(wn * 32 + 16 + lo) * SEQ + kc + hi * 8);
        acc[0][0] = __builtin_amdgcn_mfma_f32_16x16x32_bf16(a0, b0, acc[0][0], 0, 0, 0);
        acc[0][1] = __builtin_amdgcn_mfma_f32_16x16x32_bf16(a0, b1, acc[0][1], 0, 0, 0);
        acc[1][0] = __builtin_amdgcn_mfma_f32_16x16x32_bf16(a1, b0, acc[1][0], 0, 0, 0);
        acc[1][1] = __builtin_amdgcn_mfma_f32_16x16x32_bf16(a1, b1, acc[1][1], 0, 0, 0);
    }
    int b = bh >> 3, h = bh & 7;
    for (int fm = 0; fm < 2; fm++)
        for (int fn = 0; fn < 2; fn++)
            for (int rr = 0; rr < 4; rr++) {
                int ql = wm * 32 + fm * 16 + hi * 4 + rr;
                int d = wn * 32 + fn * 16 + lo;
                float val = acc[fm][fn][rr] * invS_lds[ql];
                attn[((size_t)b * SEQ + qt * 64 + ql) * DMODEL + h * DKH + d] = f2bf(val);
            }
}

// ---------------- output projection: out = attn @ Wo^T (f32 out) ----------------
__global__ __launch_bounds__(256) void oproj_kernel(const short* __restrict__ attn,
                                                    const float* __restrict__ Wo,
                                                    float* __restrict__ out) {
    __shared__ short As[64 * LDK], Bs[64 * LDK];
    int f = blockIdx.x;
    int i = f >> 3;                        // 0..63
    int mt = (f & 7) * 8 + (i >> 3);
    int nt = i & 7;
    int tid = threadIdx.x, lane = tid & 63, w = tid >> 6, wm = w >> 1, wn = w & 1;
    const short* Abase = attn + (size_t)mt * 64 * DMODEL;
    const float* Bbase = Wo + (size_t)nt * 64 * DMODEL;
    f32x4 acc[2][2] = {};
    for (int kt = 0; kt < DMODEL; kt += 32) {
        __syncthreads();
        stage_bf16(Abase + kt, DMODEL, As, tid);
        stage_f32(Bbase + kt, DMODEL, Bs, tid);
        __syncthreads();
        mma_tile(As, Bs, lane, wm, wn, acc);
    }
    int lo = lane & 15, hi = lane >> 4;
    for (int fm = 0; fm < 2; fm++)
        for (int fn = 0; fn < 2; fn++)
            for (int r = 0; r < 4; r++) {
                int m = mt * 64 + wm * 32 + fm * 16 + hi * 4 + r;
                int n = nt * 64 + wn * 32 + fn * 16 + lo;
                out[(size_t)m * DMODEL + n] = acc[fm][fn][r];
            }
}

extern "C" void kernel_launch(void* const* d_in, const int* in_sizes, int n_in,
                              void* d_out, int out_size, void* d_ws, size_t ws_size,
                              hipStream_t stream) {
    (void)in_sizes; (void)n_in; (void)out_size; (void)ws_size;
    const float* query = (const float*)d_in[0];
    const float* key   = (const float*)d_in[1];
    const float* value = (const float*)d_in[2];
    const float* rel   = (const float*)d_in[3];
    // d_in[4] = mask: deterministic causal tril, computed inline instead
    const float* Wq = (const float*)d_in[5];
    const float* Wk = (const float*)d_in[6];
    const float* Wv = (const float*)d_in[7];
    const float* Wo = (const float*)d_in[8];
    const float* Wr = (const float*)d_in[9];
    const float* u  = (const float*)d_in[10];
    const float* v  = (const float*)d_in[11];

    float* out     = (float*)d_out;                       // [8,512,512]
    float* weights = out + (size_t)BATCH * SEQ * DMODEL;  // [8,8,512,512] (scores in place)

    char* ws = (char*)d_ws;
    short* Qu   = (short*)(ws);                       // 4 MB
    short* Qv   = (short*)(ws + ((size_t)4 << 20));   // 4 MB
    short* Kh   = (short*)(ws + ((size_t)8 << 20));   // 4 MB
    short* Vt   = (short*)(ws + ((size_t)12 << 20));  // 4 MB
    short* T2   = (short*)(ws + ((size_t)16 << 20));  // 32 MB, [q][bh][n]
    short* attn = (short*)(ws + ((size_t)48 << 20));  // 4 MB
    short* Wrt  = (short*)(ws + ((size_t)52 << 20));  // 0.5 MB

    qkvw_kernel<<<1792, 256, 0, stream>>>(query, key, value, Wq, Wk, Wv, Wr,
                                          u, v, Qu, Qv, Kh, Vt, Wrt);
    tc_kernel<<<6400, 256, 0, stream>>>(Qv, Wrt, T2, Qu, Kh, weights);
    position_kernel<<<512, 1024, 0, stream>>>(T2, rel, weights);
    pv_sm_kernel<<<512, 256, 0, stream>>>(weights, Vt, attn);
    oproj_kernel<<<512, 256, 0, stream>>>(attn, Wo, out);
}

// Round 20
// 190.770 us; speedup vs baseline: 1.0880x; 1.0880x over previous
//
#include <hip/hip_runtime.h>

// Sizes (fixed by the problem)
#define BATCH   8
#define SEQ     512     // Q_LEN == K_LEN
#define DMODEL  512
#define NHEAD   8
#define DKH     64

typedef __attribute__((ext_vector_type(8))) short bf16x8;
typedef __attribute__((ext_vector_type(4))) float f32x4;

// Manual integer RNE f32->bf16 (3-4 VALU ops). Measured FASTER than
// __float2bfloat16 (R19: intrinsic cost +14us — NaN-handling selects,
// no pk-fusion). Keep manual.
__device__ __forceinline__ short f2bf(float f) {
    union { float f; unsigned u; } v; v.f = f;
    unsigned r = v.u + 0x7FFFu + ((v.u >> 16) & 1u);
    return (short)(r >> 16);
}
__device__ __forceinline__ float bf2f(short s) {
    union { unsigned u; float f; } v; v.u = ((unsigned)(unsigned short)s) << 16;
    return v.f;
}

// LDS tile: rows x 32 k (bf16), padded row stride 40 elems (80B): 2-way alias, free.
#define LDK 40

// Stage 64x32 f32 -> bf16 LDS tile. 256 threads: r=tid>>2, 8 elems each.
__device__ __forceinline__ void stage_f32(const float* __restrict__ base,
                                          int rstride, short* lds, int tid) {
    int r = tid >> 2, c = (tid & 3) << 3;
    const float* p = base + (size_t)r * rstride + c;
    float4 x = *(const float4*)p;
    float4 y = *(const float4*)(p + 4);
    union { short s[8]; bf16x8 v; } o;
    o.s[0] = f2bf(x.x); o.s[1] = f2bf(x.y); o.s[2] = f2bf(x.z); o.s[3] = f2bf(x.w);
    o.s[4] = f2bf(y.x); o.s[5] = f2bf(y.y); o.s[6] = f2bf(y.z); o.s[7] = f2bf(y.w);
    *(bf16x8*)(lds + r * LDK + c) = o.v;
}

// Stage 64x32 bf16 -> LDS tile.
__device__ __forceinline__ void stage_bf16(const short* __restrict__ base,
                                           int rstride, short* lds, int tid) {
    int r = tid >> 2, c = (tid & 3) << 3;
    bf16x8 v = *(const bf16x8*)(base + (size_t)r * rstride + c);
    *(bf16x8*)(lds + r * LDK + c) = v;
}

// One 32-deep K-step: 4 waves, each wave does a 32x32 quadrant = 4 MFMAs.
__device__ __forceinline__ void mma_tile(const short* As, const short* Bs,
                                         int lane, int wm, int wn, f32x4 acc[2][2]) {
    int lo = lane & 15, hi = lane >> 4;
    bf16x8 a0 = *(const bf16x8*)(As + (wm * 32 + lo) * LDK + hi * 8);
    bf16x8 a1 = *(const bf16x8*)(As + (wm * 32 + 16 + lo) * LDK + hi * 8);
    bf16x8 b0 = *(const bf16x8*)(Bs + (wn * 32 + lo) * LDK + hi * 8);
    bf16x8 b1 = *(const bf16x8*)(Bs + (wn * 32 + 16 + lo) * LDK + hi * 8);
    acc[0][0] = __builtin_amdgcn_mfma_f32_16x16x32_bf16(a0, b0, acc[0][0], 0, 0, 0);
    acc[0][1] = __builtin_amdgcn_mfma_f32_16x16x32_bf16(a0, b1, acc[0][1], 0, 0, 0);
    acc[1][0] = __builtin_amdgcn_mfma_f32_16x16x32_bf16(a1, b0, acc[1][0], 0, 0, 0);
    acc[1][1] = __builtin_amdgcn_mfma_f32_16x16x32_bf16(a1, b1, acc[1][1], 0, 0, 0);
}

// ---------------- Q/K/V projection + Wr transpose (merged) ----------------
__global__ __launch_bounds__(256) void qkvw_kernel(
        const float* __restrict__ query, const float* __restrict__ key_,
        const float* __restrict__ value,
        const float* __restrict__ Wq, const float* __restrict__ Wk,
        const float* __restrict__ Wv, const float* __restrict__ Wr,
        const float* __restrict__ uvec, const float* __restrict__ vvec,
        short* __restrict__ Qu, short* __restrict__ Qv,
        short* __restrict__ Kh, short* __restrict__ Vt,
        short* __restrict__ Wrt) {
    __shared__ short As[64 * LDK], Bs[64 * LDK];
    int f = blockIdx.x, tid = threadIdx.x;
    if (f >= 1536) {                       // Wr transpose path
        int base = (f - 1536) * 1024;
        #pragma unroll
        for (int j = 0; j < 4; j++) {
            int idx = base + j * 256 + tid;
            int n = idx >> 9, m = idx & 511;
            Wrt[idx] = f2bf(Wr[(size_t)m * 512 + n]);
        }
        return;
    }
    int i = f >> 3;                       // 0..191
    int nt = i & 7;
    int gm = (f & 7) * 24 + (i >> 3);     // 0..191 = (mode,mt)
    int mode = gm >> 6, mt = gm & 63;
    const float* x = mode == 0 ? query : (mode == 1 ? key_ : value);
    const float* W = mode == 0 ? Wq : (mode == 1 ? Wk : Wv);
    int lane = tid & 63, w = tid >> 6, wm = w >> 1, wn = w & 1;
    const float* Abase = x + (size_t)mt * 64 * DMODEL;
    const float* Bbase = W + (size_t)nt * 64 * DMODEL;
    f32x4 acc[2][2] = {};
    for (int kt = 0; kt < DMODEL; kt += 32) {
        __syncthreads();
        stage_f32(Abase + kt, DMODEL, As, tid);
        stage_f32(Bbase + kt, DMODEL, Bs, tid);
        __syncthreads();
        mma_tile(As, Bs, lane, wm, wn, acc);
    }
    int lo = lane & 15, hi = lane >> 4;
    for (int fm = 0; fm < 2; fm++)
        for (int fn = 0; fn < 2; fn++)
            for (int r = 0; r < 4; r++) {
                int m = mt * 64 + wm * 32 + fm * 16 + hi * 4 + r;
                int n = nt * 64 + wn * 32 + fn * 16 + lo;
                float val = acc[fm][fn][r];
                int b = m >> 9, s = m & 511, h = n >> 6, d = n & 63;
                if (mode == 0) {
                    size_t idx = ((size_t)(b * NHEAD + h) * SEQ + s) * DKH + d;
                    Qu[idx] = f2bf(val + uvec[n]);
                    Qv[idx] = f2bf(val + vvec[n]);
                } else if (mode == 1) {
                    Kh[((size_t)(b * NHEAD + h) * SEQ + s) * DKH + d] = f2bf(val);
                } else {
                    Vt[((size_t)(b * NHEAD + h) * DKH + d) * SEQ + s] = f2bf(val);
                }
            }
}

// -------- merged t + content (independent stages, one launch) --------
// blocks 0..4095:    T2[q][bh][n] = sum_d Qv[b,h,q,d] * Wrt[n][h*64+d]
// blocks 4096..6399: scores[bh,q,k] = Qu . Kh  ('=', COMPACT causal tiles:
//                    2304 = 8 XCD x 8 bh x 36 triangular (qt,kt_) pairs)
__global__ __launch_bounds__(256) void tc_kernel(const short* __restrict__ Qv,
                                                 const short* __restrict__ Wrt,
                                                 short* __restrict__ T2,
                                                 const short* __restrict__ Qu,
                                                 const short* __restrict__ Kh,
                                                 float* __restrict__ scores) {
    __shared__ short As[64 * LDK], Bs[64 * LDK];
    int f0 = blockIdx.x, tid = threadIdx.x;
    int lane = tid & 63, w = tid >> 6, wm = w >> 1, wn = w & 1;
    int lo = lane & 15, hi = lane >> 4;
    if (f0 < 4096) {                       // ---- t path ----
        int f = f0;
        int i = f >> 3;                    // 0..511
        int nt = i & 7;
        int mh = (f & 7) * 64 + (i >> 3);  // 0..511
        int mt = mh >> 3, h = mh & 7;
        int m0 = mt * 64, b = m0 >> 9, q0 = m0 & 511;
        const short* Abase = Qv + ((size_t)(b * NHEAD + h) * SEQ + q0) * DKH;
        const short* Bbase = Wrt + (size_t)nt * 64 * DMODEL + h * DKH;
        f32x4 acc[2][2] = {};
        for (int kt = 0; kt < DKH; kt += 32) {
            __syncthreads();
            stage_bf16(Abase + kt, DKH, As, tid);
            stage_bf16(Bbase + kt, DMODEL, Bs, tid);
            __syncthreads();
            mma_tile(As, Bs, lane, wm, wn, acc);
        }
        int bh = b * NHEAD + h;
        for (int fm = 0; fm < 2; fm++)
            for (int fn = 0; fn < 2; fn++)
                for (int r = 0; r < 4; r++) {
                    int q = q0 + wm * 32 + fm * 16 + hi * 4 + r;
                    int n = nt * 64 + wn * 32 + fn * 16 + lo;
                    T2[((size_t)q * 64 + bh) * DMODEL + n] = f2bf(acc[fm][fn][r]);
                }
    } else {                               // ---- content path (compacted) ----
        int i = f0 - 4096;                 // 0..2303
        int x = i & 7, j = i >> 3;         // j 0..287
        int bhl = j / 36, t = j % 36;      // 8 bh-locals x 36 causal tiles
        int bh = x * 8 + bhl;
        int qt = 0, base = 0;
        #pragma unroll
        for (int s = 1; s <= 7; s++) { if (t >= base + qt + 1) { base += qt + 1; qt++; } }
        int kt_ = t - base;                // kt_ <= qt guaranteed
        const short* Abase = Qu + ((size_t)bh * SEQ + qt * 64) * DKH;
        const short* Bbase = Kh + ((size_t)bh * SEQ + kt_ * 64) * DKH;
        f32x4 acc[2][2] = {};
        for (int kt = 0; kt < DKH; kt += 32) {
            __syncthreads();
            stage_bf16(Abase + kt, DKH, As, tid);
            stage_bf16(Bbase + kt, DKH, Bs, tid);
            __syncthreads();
            mma_tile(As, Bs, lane, wm, wn, acc);
        }
        for (int fm = 0; fm < 2; fm++)
            for (int fn = 0; fn < 2; fn++)
                for (int r = 0; r < 4; r++) {
                    int q = qt * 64 + wm * 32 + fm * 16 + hi * 4 + r;
                    int k = kt_ * 64 + wn * 32 + fn * 16 + lo;
                    scores[((size_t)bh * SEQ + q) * SEQ + k] = acc[fm][fn][r];
                }
    }
}

// ---- position v9: one q per 1024-thread block (16 waves x 32k = full row) ----
// T2[q] (64KB) staged ONCE; waves with kbase>q idle after the single barrier.
// Block pairing: q and 511-q halves balance causal load. XCD-balanced by bk&7.
__global__ __launch_bounds__(1024) void position_kernel(const short* __restrict__ T2,
                                                        const float* __restrict__ rel,
                                                        float* __restrict__ scores) {
    int bk = blockIdx.x;
    int x = bk & 7, idx = bk >> 3;         // idx 0..63
    int q = (idx < 32) ? (idx * 8 + x) : (511 - ((idx - 32) * 8 + x));
    __shared__ short Tl[64 * 512];         // 64KB
    int tid = threadIdx.x, w = tid >> 6, lane = tid & 63;
    const short* Tq = T2 + (size_t)q * (64 * DMODEL);
    #pragma unroll
    for (int it = 0; it < 4; ++it) {       // 1024 thr x 16B = 16KB/iter, sequential
        int chunk = it * 1024 + tid;       // 0..4095
        int r = chunk >> 6, c = chunk & 63;
        bf16x8 v = *(const bf16x8*)(Tq + (size_t)chunk * 8);
        *(bf16x8*)(Tl + r * 512 + (c ^ (r & 7)) * 8) = v;
    }
    __syncthreads();
    int kbase = w * 32;
    if (kbase > q) return;                 // wave-level causal skip (post-barrier)
    int lo = lane & 15, hi = lane >> 4;
    const float* relq = rel + ((size_t)kbase * SEQ + q) * DMODEL;
    f32x4 acc[4][2] = {};
    for (int n = 0; n < DMODEL; n += 32) {
        bf16x8 a[4];
        #pragma unroll
        for (int fm = 0; fm < 4; fm++) {
            int rr = fm * 16 + lo;
            int g = ((n >> 3) + hi) ^ (rr & 7);
            a[fm] = *(const bf16x8*)(Tl + rr * 512 + g * 8);
        }
        bf16x8 bfrag[2];
        #pragma unroll
        for (int fk = 0; fk < 2; fk++) {
            const float* p = relq + (size_t)(fk * 16 + lo) * (SEQ * DMODEL) + n + hi * 8;
            float4 xv = *(const float4*)p;
            float4 yv = *(const float4*)(p + 4);
            union { short s[8]; bf16x8 v; } o;
            o.s[0] = f2bf(xv.x); o.s[1] = f2bf(xv.y); o.s[2] = f2bf(xv.z); o.s[3] = f2bf(xv.w);
            o.s[4] = f2bf(yv.x); o.s[5] = f2bf(yv.y); o.s[6] = f2bf(yv.z); o.s[7] = f2bf(yv.w);
            bfrag[fk] = o.v;
        }
        #pragma unroll
        for (int fm = 0; fm < 4; fm++) {
            acc[fm][0] = __builtin_amdgcn_mfma_f32_16x16x32_bf16(a[fm], bfrag[0], acc[fm][0], 0, 0, 0);
            acc[fm][1] = __builtin_amdgcn_mfma_f32_16x16x32_bf16(a[fm], bfrag[1], acc[fm][1], 0, 0, 0);
        }
    }
    #pragma unroll
    for (int fm = 0; fm < 4; fm++)
        #pragma unroll
        for (int fk = 0; fk < 2; fk++)
            #pragma unroll
            for (int r = 0; r < 4; r++) {
                int bh = fm * 16 + hi * 4 + r;
                int k = kbase + fk * 16 + lo;
                scores[((size_t)bh * SEQ + q) * SEQ + k] += acc[fm][fk][r];
            }
}

// ------- pv_sm3: single-pass M=0 softmax + weights + PV (LDS P, Vt direct) ---
// CU-level causal balance: complementary qt across the two dispatch rounds.
#define PSTR 520
__global__ __launch_bounds__(256) void pv_sm_kernel(float* __restrict__ scores,
                                                    const short* __restrict__ Vt,
                                                    short* __restrict__ attn) {
    __shared__ short Ps[64 * PSTR];        // 66.6KB
    __shared__ float invS_lds[64];
    int f = blockIdx.x;
    int i = f >> 3;                        // 0..63 (per-XCD index)
    int bhl, qt;
    if (i < 32) { bhl = i >> 3;            qt = i & 7; }
    else        { bhl = 4 + ((i - 32) >> 3); qt = 7 - (i & 7); }
    int bh = (f & 7) * 8 + bhl;
    int tid = threadIdx.x, lane = tid & 63, w = tid >> 6, wm = w >> 1, wn = w & 1;
    int kmax = (qt + 1) * 64;
    int r = tid >> 2, c4 = tid & 3;
    int q = qt * 64 + r;
    int cc = c4 * 8;
    float* row = scores + ((size_t)bh * SEQ + q) * SEQ;
    // ---- single pass: P = exp(x/8) (M=0), S accumulate, P -> LDS ----
    float S = 0.f;
    for (int kt = 0; kt < kmax; kt += 32) {
        float4 x = *(const float4*)(row + kt + cc);
        float4 y = *(const float4*)(row + kt + cc + 4);
        float p0 = (kt + cc + 0 <= q) ? __expf(x.x * 0.125f) : 0.f;
        float p1 = (kt + cc + 1 <= q) ? __expf(x.y * 0.125f) : 0.f;
        float p2 = (kt + cc + 2 <= q) ? __expf(x.z * 0.125f) : 0.f;
        float p3 = (kt + cc + 3 <= q) ? __expf(x.w * 0.125f) : 0.f;
        float p4 = (kt + cc + 4 <= q) ? __expf(y.x * 0.125f) : 0.f;
        float p5 = (kt + cc + 5 <= q) ? __expf(y.y * 0.125f) : 0.f;
        float p6 = (kt + cc + 6 <= q) ? __expf(y.z * 0.125f) : 0.f;
        float p7 = (kt + cc + 7 <= q) ? __expf(y.w * 0.125f) : 0.f;
        S += p0 + p1 + p2 + p3 + p4 + p5 + p6 + p7;
        union { short s[8]; bf16x8 v; } o;
        o.s[0] = f2bf(p0); o.s[1] = f2bf(p1); o.s[2] = f2bf(p2); o.s[3] = f2bf(p3);
        o.s[4] = f2bf(p4); o.s[5] = f2bf(p5); o.s[6] = f2bf(p6); o.s[7] = f2bf(p7);
        *(bf16x8*)(Ps + r * PSTR + kt + cc) = o.v;
    }
    S += __shfl_xor(S, 1); S += __shfl_xor(S, 2);
    float invS = 1.0f / S;
    if (c4 == 0) invS_lds[r] = invS;
    // ---- weights write: full 512 row, normalized (zeros beyond kmax) ----
    for (int kt = 0; kt < SEQ; kt += 32) {
        float4 o0, o1;
        if (kt < kmax) {
            const short* pr = Ps + r * PSTR + kt + cc;
            o0 = make_float4(bf2f(pr[0]) * invS, bf2f(pr[1]) * invS,
                             bf2f(pr[2]) * invS, bf2f(pr[3]) * invS);
            o1 = make_float4(bf2f(pr[4]) * invS, bf2f(pr[5]) * invS,
                             bf2f(pr[6]) * invS, bf2f(pr[7]) * invS);
        } else {
            o0 = make_float4(0.f, 0.f, 0.f, 0.f); o1 = o0;
        }
        *(float4*)(row + kt + cc) = o0;
        *(float4*)(row + kt + cc + 4) = o1;
    }
    __syncthreads();                       // publish Ps + invS_lds
    // ---- PV: acc += P(LDS) x Vt(global direct), scale by invS at epilogue ----
    const short* Vtb = Vt + (size_t)bh * DKH * SEQ;
    int lo = lane & 15, hi = lane >> 4;
    f32x4 acc[2][2] = {};
    for (int kc = 0; kc < kmax; kc += 32) {
        bf16x8 a0 = *(const bf16x8*)(Ps + (wm * 32 + lo) * PSTR + kc + hi * 8);
        bf16x8 a1 = *(const bf16x8*)(Ps + (wm * 32 + 16 + lo) * PSTR + kc + hi * 8);
        bf16x8 b0 = *(const bf16x8*)(Vtb + (size_t)(wn * 32 + lo) * SEQ + kc + hi * 8);
        bf16x8 b1 = *(const bf16x8*)(Vtb + (size_t)(wn * 32 + 16 + lo) * SEQ + kc + hi * 8);
        acc[0][0] = __builtin_amdgcn_mfma_f32_16x16x32_bf16(a0, b0, acc[0][0], 0, 0, 0);
        acc[0][1] = __builtin_amdgcn_mfma_f32_16x16x32_bf16(a0, b1, acc[0][1], 0, 0, 0);
        acc[1][0] = __builtin_amdgcn_mfma_f32_16x16x32_bf16(a1, b0, acc[1][0], 0, 0, 0);
        acc[1][1] = __builtin_amdgcn_mfma_f32_16x16x32_bf16(a1, b1, acc[1][1], 0, 0, 0);
    }
    int b = bh >> 3, h = bh & 7;
    for (int fm = 0; fm < 2; fm++)
        for (int fn = 0; fn < 2; fn++)
            for (int rr = 0; rr < 4; rr++) {
                int ql = wm * 32 + fm * 16 + hi * 4 + rr;
                int d = wn * 32 + fn * 16 + lo;
                float val = acc[fm][fn][rr] * invS_lds[ql];
                attn[((size_t)b * SEQ + qt * 64 + ql) * DMODEL + h * DKH + d] = f2bf(val);
            }
}

// ---------------- output projection: out = attn @ Wo^T (f32 out) ----------------
__global__ __launch_bounds__(256) void oproj_kernel(const short* __restrict__ attn,
                                                    const float* __restrict__ Wo,
                                                    float* __restrict__ out) {
    __shared__ short As[64 * LDK], Bs[64 * LDK];
    int f = blockIdx.x;
    int i = f >> 3;                        // 0..63
    int mt = (f & 7) * 8 + (i >> 3);
    int nt = i & 7;
    int tid = threadIdx.x, lane = tid & 63, w = tid >> 6, wm = w >> 1, wn = w & 1;
    const short* Abase = attn + (size_t)mt * 64 * DMODEL;
    const float* Bbase = Wo + (size_t)nt * 64 * DMODEL;
    f32x4 acc[2][2] = {};
    for (int kt = 0; kt < DMODEL; kt += 32) {
        __syncthreads();
        stage_bf16(Abase + kt, DMODEL, As, tid);
        stage_f32(Bbase + kt, DMODEL, Bs, tid);
        __syncthreads();
        mma_tile(As, Bs, lane, wm, wn, acc);
    }
    int lo = lane & 15, hi = lane >> 4;
    for (int fm = 0; fm < 2; fm++)
        for (int fn = 0; fn < 2; fn++)
            for (int r = 0; r < 4; r++) {
                int m = mt * 64 + wm * 32 + fm * 16 + hi * 4 + r;
                int n = nt * 64 + wn * 32 + fn * 16 + lo;
                out[(size_t)m * DMODEL + n] = acc[fm][fn][r];
            }
}

extern "C" void kernel_launch(void* const* d_in, const int* in_sizes, int n_in,
                              void* d_out, int out_size, void* d_ws, size_t ws_size,
                              hipStream_t stream) {
    (void)in_sizes; (void)n_in; (void)out_size; (void)ws_size;
    const float* query = (const float*)d_in[0];
    const float* key   = (const float*)d_in[1];
    const float* value = (const float*)d_in[2];
    const float* rel   = (const float*)d_in[3];
    // d_in[4] = mask: deterministic causal tril, computed inline instead
    const float* Wq = (const float*)d_in[5];
    const float* Wk = (const float*)d_in[6];
    const float* Wv = (const float*)d_in[7];
    const float* Wo = (const float*)d_in[8];
    const float* Wr = (const float*)d_in[9];
    const float* u  = (const float*)d_in[10];
    const float* v  = (const float*)d_in[11];

    float* out     = (float*)d_out;                       // [8,512,512]
    float* weights = out + (size_t)BATCH * SEQ * DMODEL;  // [8,8,512,512] (scores in place)

    char* ws = (char*)d_ws;
    short* Qu   = (short*)(ws);                       // 4 MB
    short* Qv   = (short*)(ws + ((size_t)4 << 20));   // 4 MB
    short* Kh   = (short*)(ws + ((size_t)8 << 20));   // 4 MB
    short* Vt   = (short*)(ws + ((size_t)12 << 20));  // 4 MB
    short* T2   = (short*)(ws + ((size_t)16 << 20));  // 32 MB, [q][bh][n]
    short* attn = (short*)(ws + ((size_t)48 << 20));  // 4 MB
    short* Wrt  = (short*)(ws + ((size_t)52 << 20));  // 0.5 MB

    qkvw_kernel<<<1792, 256, 0, stream>>>(query, key, value, Wq, Wk, Wv, Wr,
                                          u, v, Qu, Qv, Kh, Vt, Wrt);
    tc_kernel<<<6400, 256, 0, stream>>>(Qv, Wrt, T2, Qu, Kh, weights);
    position_kernel<<<512, 1024, 0, stream>>>(T2, rel, weights);
    pv_sm_kernel<<<512, 256, 0, stream>>>(weights, Vt, attn);
    oproj_kernel<<<512, 256, 0, stream>>>(attn, Wo, out);
}